// Round 13
// baseline (298.741 us; speedup 1.0000x reference)
//
#include <hip/hip_runtime.h>
#include <hip/hip_fp16.h>
#include <cstdint>
#include <cstddef>

// ---------------------------------------------------------------------------
// GATv2Classifier: x(N,128) -> GATv2(2 heads,64,concat) -> elu
//                 -> GATv2(1 head,64) -> elu -> mean-pool(64 graphs) -> linear(10)
// R1..R7: pool rle; CSR gather; MFMA; edge-parallel; fp16 score; deferred
//         bias/ELU + exp2 + transposed gemm stores. 1368 -> 299us.
// R8/R9: gat software pipelining; scan fixed. 289us.
// R10: bucket-CSR + merged dispatches (13->7). 234us.
// R11: fill ILP + interleave. NEUTRAL -> fill is THROUGHPUT-bound:
//      WRITE 67MB = 27 dense + 40MB bucket line-amp (600k 4B scattered
//      stores x 64B lines, no combining across XCD L2s).
// R12: (a) cnt 1-counter-per-64B-line (test atomic same-line serialization);
//      (b) bucket capacity 40 (8MB, better cache residency; P(deg>=40)~5e-6);
//      (c) pool+head fused via last-block ticket (one fewer dispatch).
// ---------------------------------------------------------------------------

typedef __attribute__((ext_vector_type(8))) short s8v;   // 8 bf16 (4 VGPRs)
typedef __attribute__((ext_vector_type(4))) float f4v;   // MFMA accumulator

#define LOG2E 1.44269504f
#define BCAP 40                         // bucket slots per dst

__device__ __forceinline__ unsigned short f2bf(float f) {
    unsigned u = __float_as_uint(f);
    unsigned r = (u + 0x7fffu + ((u >> 16) & 1u)) >> 16;   // RNE
    return (unsigned short)r;
}
__device__ __forceinline__ __half2 habs2_(__half2 x) {
    unsigned u; __builtin_memcpy(&u, &x, 4);
    u &= 0x7fff7fffu;
    __half2 r; __builtin_memcpy(&r, &u, 4);
    return r;
}
__device__ __forceinline__ float elu_(float v) {          // exp-based ELU
    return v > 0.f ? v : exp2f(v * LOG2E) - 1.f;
}
union U4H { uint4 u; __half2 h[4]; };

// ---- dual MFMA GEMM body (transposed): mfma(Wfrag,Xfrag) => D[outch][node]
template<int CO, bool ELU_A>
__device__ __forceinline__ void gemm_dual_body(
        int blk, const void* __restrict__ Aptr,
        const unsigned short* __restrict__ Wlp, const unsigned short* __restrict__ Wrp,
        __half* __restrict__ outL, __half* __restrict__ outR,
        const float* __restrict__ att, const float* __restrict__ bias_in,
        float* __restrict__ sl06, float* __restrict__ sr06, int n) {
    constexpr int NT = CO / 16;
    constexpr int H  = CO / 64;          // heads (2 layer1, 1 layer2)
    int lane = threadIdx.x & 63;
    int node0 = blk * 64 + (threadIdx.x >> 6) * 16;
    int m = lane & 15, quad = lane >> 4;
    int row = node0 + m;                 // node this lane loads AND owns in D
    s8v a[4];
#pragma unroll
    for (int ks = 0; ks < 4; ks++) {
        union { s8v v; unsigned short u[8]; } t;
        int k0 = ks * 32 + quad * 8;
        if (row < n) {
            if (ELU_A) {
                const __half* A = (const __half*)Aptr;
                U4H raw; raw.u = *(const uint4*)(A + ((unsigned)row << 7) + k0);
                float4 bA = *(const float4*)(bias_in + k0);
                float4 bB = *(const float4*)(bias_in + k0 + 4);
                float bb[8] = {bA.x, bA.y, bA.z, bA.w, bB.x, bB.y, bB.z, bB.w};
#pragma unroll
                for (int jp = 0; jp < 4; jp++) {
                    float e0 = elu_(__low2float(raw.h[jp])  + bb[jp * 2]);
                    float e1 = elu_(__high2float(raw.h[jp]) + bb[jp * 2 + 1]);
                    t.u[jp * 2]     = f2bf(e0);
                    t.u[jp * 2 + 1] = f2bf(e1);
                }
            } else {
                const float* A = (const float*)Aptr;
                float4 fA = *(const float4*)(A + ((unsigned)row << 7) + k0);
                float4 fB = *(const float4*)(A + ((unsigned)row << 7) + k0 + 4);
                t.u[0] = f2bf(fA.x); t.u[1] = f2bf(fA.y);
                t.u[2] = f2bf(fA.z); t.u[3] = f2bf(fA.w);
                t.u[4] = f2bf(fB.x); t.u[5] = f2bf(fB.y);
                t.u[6] = f2bf(fB.z); t.u[7] = f2bf(fB.w);
            }
        } else {
#pragma unroll
            for (int j = 0; j < 8; j++) t.u[j] = 0;
        }
        a[ks] = t.v;
    }
    float dl[2] = {0.f, 0.f}, dr[2] = {0.f, 0.f};   // per-head att-dot partials
#pragma unroll
    for (int ct = 0; ct < NT; ct++) {
        f4v cl = {0.f, 0.f, 0.f, 0.f}, cr = {0.f, 0.f, 0.f, 0.f};
#pragma unroll
        for (int ks = 0; ks < 4; ks++) {
            s8v bl = *(const s8v*)(Wlp + ((size_t)(ct * 4 + ks) * 64 + lane) * 8);
            s8v br = *(const s8v*)(Wrp + ((size_t)(ct * 4 + ks) * 64 + lane) * 8);
            cl = __builtin_amdgcn_mfma_f32_16x16x32_bf16(bl, a[ks], cl, 0, 0, 0);  // SWAPPED
            cr = __builtin_amdgcn_mfma_f32_16x16x32_bf16(br, a[ks], cr, 0, 0, 0);
        }
        int ch0 = ct * 16 + quad * 4;    // 4 consecutive out-channels this lane holds
        int hh = (H == 2) ? (ct >> 2) : 0;
        float4 av = *(const float4*)(att + ch0);
        dl[hh] += av.x * cl[0] + av.y * cl[1] + av.z * cl[2] + av.w * cl[3];
        dr[hh] += av.x * cr[0] + av.y * cr[1] + av.z * cr[2] + av.w * cr[3];
        if (row < n) {
            __half2 p0 = __floats2half2_rn(cl[0], cl[1]);
            __half2 p1 = __floats2half2_rn(cl[2], cl[3]);
            __half2 q0 = __floats2half2_rn(cr[0], cr[1]);
            __half2 q1 = __floats2half2_rn(cr[2], cr[3]);
            uint2 ov, orv;
            __builtin_memcpy(&ov.x, &p0, 4);  __builtin_memcpy(&ov.y, &p1, 4);
            __builtin_memcpy(&orv.x, &q0, 4); __builtin_memcpy(&orv.y, &q1, 4);
            *(uint2*)(outL + (unsigned)row * CO + ch0) = ov;
            *(uint2*)(outR + (unsigned)row * CO + ch0) = orv;
        }
    }
#pragma unroll
    for (int h = 0; h < H; h++) {
        float vl = dl[h], vr = dr[h];
        vl += __shfl_xor(vl, 16, 64); vl += __shfl_xor(vl, 32, 64);
        vr += __shfl_xor(vr, 16, 64); vr += __shfl_xor(vr, 32, 64);
        if (quad == 0 && row < n) {
            if (H == 2) {
                sl06[((unsigned)row << 1) + h] = (0.6f * LOG2E) * vl;
                sr06[((unsigned)row << 1) + h] = (0.6f * LOG2E) * vr;
            } else {
                sl06[row] = (0.6f * LOG2E) * vl;
                sr06[row] = (0.6f * LOG2E) * vr;
            }
        }
    }
}

// ---------------- d1: weight packing + zero(cnt,spread) + zero(pooled+ticket)
__global__ void pack_zero(const float* __restrict__ Wl1, const float* __restrict__ Wr1,
                          const float* __restrict__ Wl2, const float* __restrict__ Wr2,
                          unsigned short* __restrict__ Wl1p, unsigned short* __restrict__ Wr1p,
                          unsigned short* __restrict__ Wl2p, unsigned short* __restrict__ Wr2p,
                          int* __restrict__ cnt, int ncnt, int zcb,
                          float* __restrict__ pooled, int npool) {
    int b = blockIdx.x;
    if (b >= 24) {
        if (b < 24 + zcb) {
            int i = (b - 24) * 256 + threadIdx.x;
            if (i < ncnt) cnt[i] = 0;
        } else {
            int i = (b - 24 - zcb) * 256 + threadIdx.x;
            if (i < npool) pooled[i] = 0.f;
        }
        return;
    }
    int t = b * 256 + threadIdx.x;
    const float* W; unsigned short* Wp; int CO, base;
    if      (t < 2048) { W = Wl1; Wp = Wl1p; CO = 128; base = t; }
    else if (t < 4096) { W = Wr1; Wp = Wr1p; CO = 128; base = t - 2048; }
    else if (t < 5120) { W = Wl2; Wp = Wl2p; CO = 64;  base = t - 4096; }
    else               { W = Wr2; Wp = Wr2p; CO = 64;  base = t - 5120; }
    int lane = base & 63, ks = (base >> 6) & 3, ct = base >> 8;
    int col = ct * 16 + (lane & 15);
    int k0 = ks * 32 + (lane >> 4) * 8;
    unsigned short u[8];
#pragma unroll
    for (int j = 0; j < 8; j++) u[j] = f2bf(W[(size_t)(k0 + j) * CO + col]);
    unsigned* dst = (unsigned*)(Wp + (size_t)base * 8);
    dst[0] = u[0] | ((unsigned)u[1] << 16);
    dst[1] = u[2] | ((unsigned)u[3] << 16);
    dst[2] = u[4] | ((unsigned)u[5] << 16);
    dst[3] = u[6] | ((unsigned)u[7] << 16);
}

// ---------------- d2: interleaved gemm1 (even blocks) + fill (odd blocks) ---
// cnt spread: one counter per 64B line (cnt[d<<4]) -- kills same-line
// atomic serialization. bucket stride BCAP=40.
__global__ void gemm1_fill(const float* __restrict__ x,
                           const unsigned short* __restrict__ Wl1p,
                           const unsigned short* __restrict__ Wr1p,
                           __half* __restrict__ xl1, __half* __restrict__ xr1,
                           const float* __restrict__ att1,
                           float* __restrict__ sl1, float* __restrict__ sr1, int n,
                           int GB, int FBn,
                           const int* __restrict__ srcA, const int* __restrict__ dstA, int E,
                           int* __restrict__ cnt, int* __restrict__ bucket) {
    int b = blockIdx.x;
    if ((b & 1) == 0) {
        int g = b >> 1;
        if (g < GB)
            gemm_dual_body<128, false>(g, x, Wl1p, Wr1p, xl1, xr1,
                                       att1, nullptr, sl1, sr1, n);
        return;
    }
    int f = b >> 1;
    if (f >= FBn) return;
    int t0 = f * 256 + threadIdx.x;
    int Q = FBn * 256;
#pragma unroll
    for (int k = 0; k < 4; k++) {
        int i = t0 + k * Q;
        if (i < E) {
            int d = dstA[i];
            int pos = atomicAdd(&cnt[d << 4], 1);   // deg<=~35 < BCAP
            bucket[d * BCAP + pos] = srcA[i];
        }
    }
}

__global__ void gemm2(const __half* __restrict__ h1,
                      const unsigned short* __restrict__ Wl2p,
                      const unsigned short* __restrict__ Wr2p,
                      __half* __restrict__ xl2, __half* __restrict__ xr2,
                      const float* __restrict__ att2, const float* __restrict__ b1,
                      float* __restrict__ sl2, float* __restrict__ sr2, int n) {
    gemm_dual_body<64, true>(blockIdx.x, h1, Wl2p, Wr2p, xl2, xr2,
                             att2, b1, sl2, sr2, n);
}

// ---------------- fused GATv2 layer 1: 4 edges/iter, 2-stage pipeline -------
__global__ void gat1_fused(const __half* __restrict__ xl, const __half* __restrict__ xr,
                           const float* __restrict__ sl06, const float* __restrict__ sr06,
                           const float* __restrict__ att,
                           const int* __restrict__ cnt, const int* __restrict__ bucket,
                           __half* __restrict__ h1, int n) {
    int d = (blockIdx.x * blockDim.x + threadIdx.x) >> 6;
    if (d >= n) return;
    int lane = threadIdx.x & 63;
    int e = lane >> 4;                  // edge slot 0..3
    int h = (lane >> 3) & 1;            // head
    int off = h * 64 + (lane & 7) * 8;  // 8-channel base
    U4H xv; xv.u = *(const uint4*)(xr + (((unsigned)d << 7) + off));
    float4 aA = *(const float4*)(att + off);
    float4 aB = *(const float4*)(att + off + 4);
    const float S = 0.4f * LOG2E;
    __half2 a2[4];
    a2[0] = __floats2half2_rn(S * aA.x, S * aA.y);
    a2[1] = __floats2half2_rn(S * aA.z, S * aA.w);
    a2[2] = __floats2half2_rn(S * aB.x, S * aB.y);
    a2[3] = __floats2half2_rn(S * aB.z, S * aB.w);
    float srd = sr06[((unsigned)d << 1) + h];
    float c0 = 0.f, c1 = 0.f, c2 = 0.f, c3 = 0.f;
    float c4 = 0.f, c5 = 0.f, c6 = 0.f, c7 = 0.f, den = 0.f;
    int deg = cnt[d << 4];
    int bb = d * BCAP;
    int j0 = -1 + e;
    int s0 = bucket[bb + max(j0, 0)];               s0 = (j0 >= 0 && j0 < deg) ? s0 : d;
    int j1 = j0 + 4;
    int s1 = bucket[bb + min(max(j1, 0), BCAP - 1)]; s1 = (j1 >= 0 && j1 < deg) ? s1 : d;
    int j2 = j0 + 8;
    int s2 = bucket[bb + min(max(j2, 0), BCAP - 1)]; s2 = (j2 >= 0 && j2 < deg) ? s2 : d;
    U4H xc;  xc.u  = *(const uint4*)(xl + (((unsigned)s0 << 7) + off));
    float slc = sl06[((unsigned)s0 << 1) + h];
    U4H xn1; xn1.u = *(const uint4*)(xl + (((unsigned)s1 << 7) + off));
    float sln1 = sl06[((unsigned)s1 << 1) + h];
    for (int base = -1; base < deg; base += 4) {
        U4H xn2; xn2.u = *(const uint4*)(xl + (((unsigned)s2 << 7) + off));
        float sln2 = sl06[((unsigned)s2 << 1) + h];
        int j3 = base + 12 + e;
        int s3 = bucket[bb + min(max(j3, 0), BCAP - 1)];
        s3 = (j3 >= 0 && j3 < deg) ? s3 : d;
        bool valid = (base + e) < deg;
        __half2 sc = __floats2half2_rn(0.f, 0.f);
        sc = __hfma2(a2[0], habs2_(__hadd2(xc.h[0], xv.h[0])), sc);
        sc = __hfma2(a2[1], habs2_(__hadd2(xc.h[1], xv.h[1])), sc);
        sc = __hfma2(a2[2], habs2_(__hadd2(xc.h[2], xv.h[2])), sc);
        sc = __hfma2(a2[3], habs2_(__hadd2(xc.h[3], xv.h[3])), sc);
        float v = __low2float(sc) + __high2float(sc);
        v += __shfl_xor(v, 1, 64); v += __shfl_xor(v, 2, 64); v += __shfl_xor(v, 4, 64);
        float p = valid ? exp2f(slc + srd + v) : 0.f;
        c0 = fmaf(__low2float(xc.h[0]),  p, c0);
        c1 = fmaf(__high2float(xc.h[0]), p, c1);
        c2 = fmaf(__low2float(xc.h[1]),  p, c2);
        c3 = fmaf(__high2float(xc.h[1]), p, c3);
        c4 = fmaf(__low2float(xc.h[2]),  p, c4);
        c5 = fmaf(__high2float(xc.h[2]), p, c5);
        c6 = fmaf(__low2float(xc.h[3]),  p, c6);
        c7 = fmaf(__high2float(xc.h[3]), p, c7);
        den += p;
        xc = xn1; slc = sln1; xn1 = xn2; sln1 = sln2; s2 = s3;
    }
#pragma unroll
    for (int o = 16; o <= 32; o <<= 1) {
        c0 += __shfl_xor(c0, o, 64); c1 += __shfl_xor(c1, o, 64);
        c2 += __shfl_xor(c2, o, 64); c3 += __shfl_xor(c3, o, 64);
        c4 += __shfl_xor(c4, o, 64); c5 += __shfl_xor(c5, o, 64);
        c6 += __shfl_xor(c6, o, 64); c7 += __shfl_xor(c7, o, 64);
        den += __shfl_xor(den, o, 64);
    }
    if (e == 0) {
        float r = 1.f / den;
        __half2 o0 = __floats2half2_rn(c0 * r, c1 * r);
        __half2 o1 = __floats2half2_rn(c2 * r, c3 * r);
        __half2 o2 = __floats2half2_rn(c4 * r, c5 * r);
        __half2 o3 = __floats2half2_rn(c6 * r, c7 * r);
        uint4 out;
        __builtin_memcpy(&out.x, &o0, 4); __builtin_memcpy(&out.y, &o1, 4);
        __builtin_memcpy(&out.z, &o2, 4); __builtin_memcpy(&out.w, &o3, 4);
        *(uint4*)(h1 + (((unsigned)d << 7) + off)) = out;
    }
}

// ---------------- fused GATv2 layer 2: 8 edges/iter, 2-stage pipeline -------
__global__ void gat2_fused(const __half* __restrict__ xl, const __half* __restrict__ xr,
                           const float* __restrict__ sl06, const float* __restrict__ sr06,
                           const float* __restrict__ att,
                           const int* __restrict__ cnt, const int* __restrict__ bucket,
                           float* __restrict__ h2, int n) {
    int d = (blockIdx.x * blockDim.x + threadIdx.x) >> 6;
    if (d >= n) return;
    int lane = threadIdx.x & 63;
    int e = lane >> 3;                  // edge slot 0..7
    int off = (lane & 7) * 8;           // 8-channel base
    U4H xv; xv.u = *(const uint4*)(xr + (((unsigned)d << 6) + off));
    float4 aA = *(const float4*)(att + off);
    float4 aB = *(const float4*)(att + off + 4);
    const float S = 0.4f * LOG2E;
    __half2 a2[4];
    a2[0] = __floats2half2_rn(S * aA.x, S * aA.y);
    a2[1] = __floats2half2_rn(S * aA.z, S * aA.w);
    a2[2] = __floats2half2_rn(S * aB.x, S * aB.y);
    a2[3] = __floats2half2_rn(S * aB.z, S * aB.w);
    float srd = sr06[d];
    float c0 = 0.f, c1 = 0.f, c2 = 0.f, c3 = 0.f;
    float c4 = 0.f, c5 = 0.f, c6 = 0.f, c7 = 0.f, den = 0.f;
    int deg = cnt[d << 4];
    int bb = d * BCAP;
    int j0 = -1 + e;
    int s0 = bucket[bb + max(j0, 0)];               s0 = (j0 >= 0 && j0 < deg) ? s0 : d;
    int j1 = j0 + 8;
    int s1 = bucket[bb + min(max(j1, 0), BCAP - 1)]; s1 = (j1 >= 0 && j1 < deg) ? s1 : d;
    int j2 = j0 + 16;
    int s2 = bucket[bb + min(max(j2, 0), BCAP - 1)]; s2 = (j2 >= 0 && j2 < deg) ? s2 : d;
    U4H xc;  xc.u  = *(const uint4*)(xl + (((unsigned)s0 << 6) + off));
    float slc = sl06[s0];
    U4H xn1; xn1.u = *(const uint4*)(xl + (((unsigned)s1 << 6) + off));
    float sln1 = sl06[s1];
    for (int base = -1; base < deg; base += 8) {
        U4H xn2; xn2.u = *(const uint4*)(xl + (((unsigned)s2 << 6) + off));
        float sln2 = sl06[s2];
        int j3 = base + 24 + e;
        int s3 = bucket[bb + min(max(j3, 0), BCAP - 1)];
        s3 = (j3 >= 0 && j3 < deg) ? s3 : d;
        bool valid = (base + e) < deg;
        __half2 sc = __floats2half2_rn(0.f, 0.f);
        sc = __hfma2(a2[0], habs2_(__hadd2(xc.h[0], xv.h[0])), sc);
        sc = __hfma2(a2[1], habs2_(__hadd2(xc.h[1], xv.h[1])), sc);
        sc = __hfma2(a2[2], habs2_(__hadd2(xc.h[2], xv.h[2])), sc);
        sc = __hfma2(a2[3], habs2_(__hadd2(xc.h[3], xv.h[3])), sc);
        float v = __low2float(sc) + __high2float(sc);
        v += __shfl_xor(v, 1, 64); v += __shfl_xor(v, 2, 64); v += __shfl_xor(v, 4, 64);
        float p = valid ? exp2f(slc + srd + v) : 0.f;
        c0 = fmaf(__low2float(xc.h[0]),  p, c0);
        c1 = fmaf(__high2float(xc.h[0]), p, c1);
        c2 = fmaf(__low2float(xc.h[1]),  p, c2);
        c3 = fmaf(__high2float(xc.h[1]), p, c3);
        c4 = fmaf(__low2float(xc.h[2]),  p, c4);
        c5 = fmaf(__high2float(xc.h[2]), p, c5);
        c6 = fmaf(__low2float(xc.h[3]),  p, c6);
        c7 = fmaf(__high2float(xc.h[3]), p, c7);
        den += p;
        xc = xn1; slc = sln1; xn1 = xn2; sln1 = sln2; s2 = s3;
    }
#pragma unroll
    for (int o = 8; o <= 32; o <<= 1) {
        c0 += __shfl_xor(c0, o, 64); c1 += __shfl_xor(c1, o, 64);
        c2 += __shfl_xor(c2, o, 64); c3 += __shfl_xor(c3, o, 64);
        c4 += __shfl_xor(c4, o, 64); c5 += __shfl_xor(c5, o, 64);
        c6 += __shfl_xor(c6, o, 64); c7 += __shfl_xor(c7, o, 64);
        den += __shfl_xor(den, o, 64);
    }
    if (e == 0) {
        float r = 1.f / den;
        float4 A = {c0 * r, c1 * r, c2 * r, c3 * r};
        float4 B = {c4 * r, c5 * r, c6 * r, c7 * r};
        *(float4*)(h2 + (((unsigned)d << 6) + off))     = A;
        *(float4*)(h2 + (((unsigned)d << 6) + off + 4)) = B;
    }
}

// ---- pool (elu(h+b2), rle over sorted batch) + head, fused via last-block
// ticket: every block increments ticket after a fence; the block that sees
// ticket==nblocks-1 computes the 64x10 head (agent-scope atomic loads --
// pooled was written with device-scope atomics, so values are at the
// coherent point). No spinning -> no dispatch-order deadlock risk.
__global__ void pool_head(const float* __restrict__ h, const float* __restrict__ b2,
                          const int* __restrict__ batch, int n, int chunk,
                          float* __restrict__ pooled, float* __restrict__ counts,
                          const float* __restrict__ Wlin, const float* __restrict__ blin,
                          float* __restrict__ out, int NC, int NG,
                          int* __restrict__ ticket, int nblocks) {
    int w = (blockIdx.x * blockDim.x + threadIdx.x) >> 6;
    int lane = threadIdx.x & 63;
    int start = w * chunk;
    int end = min(n, start + chunk);
    if (start < end) {
        float bv = b2[lane];
        int cur = batch[start];
        float acc = 0.f, cnt = 0.f;
        for (int node = start; node < end; node++) {
            int g = batch[node];
            if (g != cur) {
                atomicAdd(&pooled[(size_t)cur * 64 + lane], acc);
                if (lane == 0) atomicAdd(&counts[cur], cnt);
                acc = 0.f; cnt = 0.f; cur = g;
            }
            acc += elu_(h[((unsigned)node << 6) + lane] + bv);
            cnt += 1.f;
        }
        atomicAdd(&pooled[(size_t)cur * 64 + lane], acc);
        if (lane == 0) atomicAdd(&counts[cur], cnt);
    }
    __threadfence();
    __syncthreads();
    __shared__ int lastv;
    if (threadIdx.x == 0) lastv = (atomicAdd(ticket, 1) == nblocks - 1) ? 1 : 0;
    __syncthreads();
    if (!lastv) return;
    int wv = threadIdx.x >> 6;          // 4 waves x 16 graphs each
    for (int g = wv; g < NG; g += 4) {
        float cg = __hip_atomic_load(&counts[g], __ATOMIC_RELAXED,
                                     __HIP_MEMORY_SCOPE_AGENT);
        float pv = __hip_atomic_load(&pooled[(size_t)g * 64 + lane], __ATOMIC_RELAXED,
                                     __HIP_MEMORY_SCOPE_AGENT);
        float v = pv / fmaxf(cg, 1.f);
        for (int j = 0; j < NC; j++) {
            float t = v * Wlin[lane * NC + j];
            for (int off = 32; off > 0; off >>= 1) t += __shfl_down(t, off, 64);
            if (lane == 0) out[g * NC + j] = t + blin[j];
        }
    }
}

extern "C" void kernel_launch(void* const* d_in, const int* in_sizes, int n_in,
                              void* d_out, int out_size, void* d_ws, size_t ws_size,
                              hipStream_t stream) {
    const float* x    = (const float*)d_in[0];
    const int*   ei   = (const int*)d_in[1];
    const int*   batch= (const int*)d_in[2];
    const float* Wl1  = (const float*)d_in[3];
    const float* Wr1  = (const float*)d_in[4];
    const float* att1 = (const float*)d_in[5];
    const float* b1   = (const float*)d_in[6];
    const float* Wl2  = (const float*)d_in[7];
    const float* Wr2  = (const float*)d_in[8];
    const float* att2 = (const float*)d_in[9];
    const float* b2   = (const float*)d_in[10];
    const float* Wlin = (const float*)d_in[11];
    const float* blin = (const float*)d_in[12];

    const int n    = in_sizes[0] / 128;   // 50000
    const int E    = in_sizes[1] / 2;     // 600000
    const int NC   = in_sizes[12];        // 10
    const int NG   = out_size / NC;       // 64

    const int* srcA = ei;
    const int* dstA = ei + E;

    // ---- workspace layout (bytes). Aliasing: xl2+xr2 fill xl1's region,
    //      h2 fills xr1's. h1 (fp16) is kept live through gemm2.
    uint8_t* w = (uint8_t*)d_ws;
    const size_t rowB = (size_t)n * 128 * 2;     // one N x 128 16-bit tensor
    __half*         xl1 = (__half*)w;
    __half*         xr1 = (__half*)(w + rowB);
    __half*         h1  = (__half*)(w + 2 * rowB);
    __half*         xl2 = (__half*)w;                           // n*64 fp16
    __half*         xr2 = (__half*)(w + (size_t)n * 64 * 2);
    float*          h2  = (float*)(w + rowB);                   // n*64 fp32
    uint8_t* fx = w + 3 * rowB;
    unsigned short* Wl1p = (unsigned short*)fx;            fx += 16384 * 2;
    unsigned short* Wr1p = (unsigned short*)fx;            fx += 16384 * 2;
    unsigned short* Wl2p = (unsigned short*)fx;            fx += 8192 * 2;
    unsigned short* Wr2p = (unsigned short*)fx;            fx += 8192 * 2;
    float* sl1 = (float*)fx;                               fx += (size_t)n * 2 * 4;
    float* sr1 = (float*)fx;                               fx += (size_t)n * 2 * 4;
    float* sl2 = (float*)fx;                               fx += (size_t)n * 4;
    float* sr2 = (float*)fx;                               fx += (size_t)n * 4;
    float* pooled = (float*)fx;                            fx += (size_t)NG * 64 * 4;
    float* counts = (float*)fx;                            fx += (size_t)NG * 4;
    int* ticket = (int*)fx;                                fx += 4;
    int* cnt    = (int*)fx;                                fx += (size_t)n * 16 * 4;
    int* bucket = (int*)fx;                                fx += ((size_t)n * BCAP + 64) * 4;
    if (ws_size < (size_t)(fx - (uint8_t*)d_ws)) return;   // bail visibly

    const int GB  = (n + 63) / 64;       // gemm blocks (64 nodes each)
    const int FBn = (E + 1023) / 1024;   // fill blocks (4 edges/thread)
    const int ncnt = n * 16;             // spread counters (1 per 64B line)
    const int zcb = (ncnt + 255) / 256;
    const int npool = NG * 65 + 1;       // pooled + counts + ticket (contiguous)
    const int pzb = (npool + 255) / 256;
    const int dblocks = (n + 3) / 4;     // 4 dst-waves per 256-thread block
    const int T2 = 2 * ((GB > FBn) ? GB : FBn);

    // d1: pack weights + zero cnt + zero pooled/counts/ticket
    pack_zero<<<24 + zcb + pzb, 256, 0, stream>>>(Wl1, Wr1, Wl2, Wr2,
                                                  Wl1p, Wr1p, Wl2p, Wr2p,
                                                  cnt, ncnt, zcb, pooled, npool);
    // d2: gemm layer-1 || bucket fill, interleaved even/odd
    gemm1_fill<<<T2, 256, 0, stream>>>(x, Wl1p, Wr1p, xl1, xr1, att1,
                                       sl1, sr1, n, GB, FBn,
                                       srcA, dstA, E, cnt, bucket);
    // d3..d6
    gat1_fused<<<dblocks, 256, 0, stream>>>(xl1, xr1, sl1, sr1, att1,
                                            cnt, bucket, h1, n);
    gemm2<<<GB, 256, 0, stream>>>(h1, Wl2p, Wr2p, xl2, xr2, att2, b1, sl2, sr2, n);
    gat2_fused<<<dblocks, 256, 0, stream>>>(xl2, xr2, sl2, sr2, att2,
                                            cnt, bucket, h2, n);
    {
        const int nwaves = 1024;
        const int chunk = (n + nwaves - 1) / nwaves;
        pool_head<<<256, 256, 0, stream>>>(h2, b2, batch, n, chunk, pooled, counts,
                                           Wlin, blin, (float*)d_out, NC, NG,
                                           ticket, 256);
    }
}

// Round 14
// 230.887 us; speedup vs baseline: 1.2939x; 1.2939x over previous
//
#include <hip/hip_runtime.h>
#include <hip/hip_fp16.h>
#include <cstdint>
#include <cstddef>

// ---------------------------------------------------------------------------
// GATv2Classifier: x(N,128) -> GATv2(2 heads,64,concat) -> elu
//                 -> GATv2(1 head,64) -> elu -> mean-pool(64 graphs) -> linear(10)
// R1..R7: pool rle; CSR gather; MFMA; edge-parallel; fp16 score; deferred
//         bias/ELU + exp2 + transposed gemm stores. 1368 -> 299us.
// R8/R9: gat software pipelining; scan fixed. 289us.
// R10: bucket-CSR + merged dispatches (13->7). 234us.
// R11: fill ILP + interleave. NEUTRAL (fill = scatter write-amp floor). 236us.
// R12: cnt-spread + BCAP=40 (neutral) + pool/head ticket fusion: REGRESSED
//      -- __threadfence() in-kernel = cross-XCD L2 writeback, 256 blocks x
//      ~0.35us serialized = +85us on pool_head. 298.7us.
// R13: revert ONLY the fusion: pool_rle + head as separate dispatches (the
//      kernel boundary is the free coherence point on CDNA4). Keep the rest.
// ---------------------------------------------------------------------------

typedef __attribute__((ext_vector_type(8))) short s8v;   // 8 bf16 (4 VGPRs)
typedef __attribute__((ext_vector_type(4))) float f4v;   // MFMA accumulator

#define LOG2E 1.44269504f
#define BCAP 40                         // bucket slots per dst

__device__ __forceinline__ unsigned short f2bf(float f) {
    unsigned u = __float_as_uint(f);
    unsigned r = (u + 0x7fffu + ((u >> 16) & 1u)) >> 16;   // RNE
    return (unsigned short)r;
}
__device__ __forceinline__ __half2 habs2_(__half2 x) {
    unsigned u; __builtin_memcpy(&u, &x, 4);
    u &= 0x7fff7fffu;
    __half2 r; __builtin_memcpy(&r, &u, 4);
    return r;
}
__device__ __forceinline__ float elu_(float v) {          // exp-based ELU
    return v > 0.f ? v : exp2f(v * LOG2E) - 1.f;
}
union U4H { uint4 u; __half2 h[4]; };

// ---- dual MFMA GEMM body (transposed): mfma(Wfrag,Xfrag) => D[outch][node]
template<int CO, bool ELU_A>
__device__ __forceinline__ void gemm_dual_body(
        int blk, const void* __restrict__ Aptr,
        const unsigned short* __restrict__ Wlp, const unsigned short* __restrict__ Wrp,
        __half* __restrict__ outL, __half* __restrict__ outR,
        const float* __restrict__ att, const float* __restrict__ bias_in,
        float* __restrict__ sl06, float* __restrict__ sr06, int n) {
    constexpr int NT = CO / 16;
    constexpr int H  = CO / 64;          // heads (2 layer1, 1 layer2)
    int lane = threadIdx.x & 63;
    int node0 = blk * 64 + (threadIdx.x >> 6) * 16;
    int m = lane & 15, quad = lane >> 4;
    int row = node0 + m;                 // node this lane loads AND owns in D
    s8v a[4];
#pragma unroll
    for (int ks = 0; ks < 4; ks++) {
        union { s8v v; unsigned short u[8]; } t;
        int k0 = ks * 32 + quad * 8;
        if (row < n) {
            if (ELU_A) {
                const __half* A = (const __half*)Aptr;
                U4H raw; raw.u = *(const uint4*)(A + ((unsigned)row << 7) + k0);
                float4 bA = *(const float4*)(bias_in + k0);
                float4 bB = *(const float4*)(bias_in + k0 + 4);
                float bb[8] = {bA.x, bA.y, bA.z, bA.w, bB.x, bB.y, bB.z, bB.w};
#pragma unroll
                for (int jp = 0; jp < 4; jp++) {
                    float e0 = elu_(__low2float(raw.h[jp])  + bb[jp * 2]);
                    float e1 = elu_(__high2float(raw.h[jp]) + bb[jp * 2 + 1]);
                    t.u[jp * 2]     = f2bf(e0);
                    t.u[jp * 2 + 1] = f2bf(e1);
                }
            } else {
                const float* A = (const float*)Aptr;
                float4 fA = *(const float4*)(A + ((unsigned)row << 7) + k0);
                float4 fB = *(const float4*)(A + ((unsigned)row << 7) + k0 + 4);
                t.u[0] = f2bf(fA.x); t.u[1] = f2bf(fA.y);
                t.u[2] = f2bf(fA.z); t.u[3] = f2bf(fA.w);
                t.u[4] = f2bf(fB.x); t.u[5] = f2bf(fB.y);
                t.u[6] = f2bf(fB.z); t.u[7] = f2bf(fB.w);
            }
        } else {
#pragma unroll
            for (int j = 0; j < 8; j++) t.u[j] = 0;
        }
        a[ks] = t.v;
    }
    float dl[2] = {0.f, 0.f}, dr[2] = {0.f, 0.f};   // per-head att-dot partials
#pragma unroll
    for (int ct = 0; ct < NT; ct++) {
        f4v cl = {0.f, 0.f, 0.f, 0.f}, cr = {0.f, 0.f, 0.f, 0.f};
#pragma unroll
        for (int ks = 0; ks < 4; ks++) {
            s8v bl = *(const s8v*)(Wlp + ((size_t)(ct * 4 + ks) * 64 + lane) * 8);
            s8v br = *(const s8v*)(Wrp + ((size_t)(ct * 4 + ks) * 64 + lane) * 8);
            cl = __builtin_amdgcn_mfma_f32_16x16x32_bf16(bl, a[ks], cl, 0, 0, 0);  // SWAPPED
            cr = __builtin_amdgcn_mfma_f32_16x16x32_bf16(br, a[ks], cr, 0, 0, 0);
        }
        int ch0 = ct * 16 + quad * 4;    // 4 consecutive out-channels this lane holds
        int hh = (H == 2) ? (ct >> 2) : 0;
        float4 av = *(const float4*)(att + ch0);
        dl[hh] += av.x * cl[0] + av.y * cl[1] + av.z * cl[2] + av.w * cl[3];
        dr[hh] += av.x * cr[0] + av.y * cr[1] + av.z * cr[2] + av.w * cr[3];
        if (row < n) {
            __half2 p0 = __floats2half2_rn(cl[0], cl[1]);
            __half2 p1 = __floats2half2_rn(cl[2], cl[3]);
            __half2 q0 = __floats2half2_rn(cr[0], cr[1]);
            __half2 q1 = __floats2half2_rn(cr[2], cr[3]);
            uint2 ov, orv;
            __builtin_memcpy(&ov.x, &p0, 4);  __builtin_memcpy(&ov.y, &p1, 4);
            __builtin_memcpy(&orv.x, &q0, 4); __builtin_memcpy(&orv.y, &q1, 4);
            *(uint2*)(outL + (unsigned)row * CO + ch0) = ov;
            *(uint2*)(outR + (unsigned)row * CO + ch0) = orv;
        }
    }
#pragma unroll
    for (int h = 0; h < H; h++) {
        float vl = dl[h], vr = dr[h];
        vl += __shfl_xor(vl, 16, 64); vl += __shfl_xor(vl, 32, 64);
        vr += __shfl_xor(vr, 16, 64); vr += __shfl_xor(vr, 32, 64);
        if (quad == 0 && row < n) {
            if (H == 2) {
                sl06[((unsigned)row << 1) + h] = (0.6f * LOG2E) * vl;
                sr06[((unsigned)row << 1) + h] = (0.6f * LOG2E) * vr;
            } else {
                sl06[row] = (0.6f * LOG2E) * vl;
                sr06[row] = (0.6f * LOG2E) * vr;
            }
        }
    }
}

// ---------------- d1: weight packing + zero(cnt,spread) + zero(pooled) ------
__global__ void pack_zero(const float* __restrict__ Wl1, const float* __restrict__ Wr1,
                          const float* __restrict__ Wl2, const float* __restrict__ Wr2,
                          unsigned short* __restrict__ Wl1p, unsigned short* __restrict__ Wr1p,
                          unsigned short* __restrict__ Wl2p, unsigned short* __restrict__ Wr2p,
                          int* __restrict__ cnt, int ncnt, int zcb,
                          float* __restrict__ pooled, int npool) {
    int b = blockIdx.x;
    if (b >= 24) {
        if (b < 24 + zcb) {
            int i = (b - 24) * 256 + threadIdx.x;
            if (i < ncnt) cnt[i] = 0;
        } else {
            int i = (b - 24 - zcb) * 256 + threadIdx.x;
            if (i < npool) pooled[i] = 0.f;
        }
        return;
    }
    int t = b * 256 + threadIdx.x;
    const float* W; unsigned short* Wp; int CO, base;
    if      (t < 2048) { W = Wl1; Wp = Wl1p; CO = 128; base = t; }
    else if (t < 4096) { W = Wr1; Wp = Wr1p; CO = 128; base = t - 2048; }
    else if (t < 5120) { W = Wl2; Wp = Wl2p; CO = 64;  base = t - 4096; }
    else               { W = Wr2; Wp = Wr2p; CO = 64;  base = t - 5120; }
    int lane = base & 63, ks = (base >> 6) & 3, ct = base >> 8;
    int col = ct * 16 + (lane & 15);
    int k0 = ks * 32 + (lane >> 4) * 8;
    unsigned short u[8];
#pragma unroll
    for (int j = 0; j < 8; j++) u[j] = f2bf(W[(size_t)(k0 + j) * CO + col]);
    unsigned* dst = (unsigned*)(Wp + (size_t)base * 8);
    dst[0] = u[0] | ((unsigned)u[1] << 16);
    dst[1] = u[2] | ((unsigned)u[3] << 16);
    dst[2] = u[4] | ((unsigned)u[5] << 16);
    dst[3] = u[6] | ((unsigned)u[7] << 16);
}

// ---------------- d2: interleaved gemm1 (even blocks) + fill (odd blocks) ---
__global__ void gemm1_fill(const float* __restrict__ x,
                           const unsigned short* __restrict__ Wl1p,
                           const unsigned short* __restrict__ Wr1p,
                           __half* __restrict__ xl1, __half* __restrict__ xr1,
                           const float* __restrict__ att1,
                           float* __restrict__ sl1, float* __restrict__ sr1, int n,
                           int GB, int FBn,
                           const int* __restrict__ srcA, const int* __restrict__ dstA, int E,
                           int* __restrict__ cnt, int* __restrict__ bucket) {
    int b = blockIdx.x;
    if ((b & 1) == 0) {
        int g = b >> 1;
        if (g < GB)
            gemm_dual_body<128, false>(g, x, Wl1p, Wr1p, xl1, xr1,
                                       att1, nullptr, sl1, sr1, n);
        return;
    }
    int f = b >> 1;
    if (f >= FBn) return;
    int t0 = f * 256 + threadIdx.x;
    int Q = FBn * 256;
#pragma unroll
    for (int k = 0; k < 4; k++) {
        int i = t0 + k * Q;
        if (i < E) {
            int d = dstA[i];
            int pos = atomicAdd(&cnt[d << 4], 1);   // deg<=~35 < BCAP
            bucket[d * BCAP + pos] = srcA[i];
        }
    }
}

__global__ void gemm2(const __half* __restrict__ h1,
                      const unsigned short* __restrict__ Wl2p,
                      const unsigned short* __restrict__ Wr2p,
                      __half* __restrict__ xl2, __half* __restrict__ xr2,
                      const float* __restrict__ att2, const float* __restrict__ b1,
                      float* __restrict__ sl2, float* __restrict__ sr2, int n) {
    gemm_dual_body<64, true>(blockIdx.x, h1, Wl2p, Wr2p, xl2, xr2,
                             att2, b1, sl2, sr2, n);
}

// ---------------- fused GATv2 layer 1: 4 edges/iter, 2-stage pipeline -------
__global__ void gat1_fused(const __half* __restrict__ xl, const __half* __restrict__ xr,
                           const float* __restrict__ sl06, const float* __restrict__ sr06,
                           const float* __restrict__ att,
                           const int* __restrict__ cnt, const int* __restrict__ bucket,
                           __half* __restrict__ h1, int n) {
    int d = (blockIdx.x * blockDim.x + threadIdx.x) >> 6;
    if (d >= n) return;
    int lane = threadIdx.x & 63;
    int e = lane >> 4;                  // edge slot 0..3
    int h = (lane >> 3) & 1;            // head
    int off = h * 64 + (lane & 7) * 8;  // 8-channel base
    U4H xv; xv.u = *(const uint4*)(xr + (((unsigned)d << 7) + off));
    float4 aA = *(const float4*)(att + off);
    float4 aB = *(const float4*)(att + off + 4);
    const float S = 0.4f * LOG2E;
    __half2 a2[4];
    a2[0] = __floats2half2_rn(S * aA.x, S * aA.y);
    a2[1] = __floats2half2_rn(S * aA.z, S * aA.w);
    a2[2] = __floats2half2_rn(S * aB.x, S * aB.y);
    a2[3] = __floats2half2_rn(S * aB.z, S * aB.w);
    float srd = sr06[((unsigned)d << 1) + h];
    float c0 = 0.f, c1 = 0.f, c2 = 0.f, c3 = 0.f;
    float c4 = 0.f, c5 = 0.f, c6 = 0.f, c7 = 0.f, den = 0.f;
    int deg = cnt[d << 4];
    int bb = d * BCAP;
    int j0 = -1 + e;
    int s0 = bucket[bb + max(j0, 0)];               s0 = (j0 >= 0 && j0 < deg) ? s0 : d;
    int j1 = j0 + 4;
    int s1 = bucket[bb + min(max(j1, 0), BCAP - 1)]; s1 = (j1 >= 0 && j1 < deg) ? s1 : d;
    int j2 = j0 + 8;
    int s2 = bucket[bb + min(max(j2, 0), BCAP - 1)]; s2 = (j2 >= 0 && j2 < deg) ? s2 : d;
    U4H xc;  xc.u  = *(const uint4*)(xl + (((unsigned)s0 << 7) + off));
    float slc = sl06[((unsigned)s0 << 1) + h];
    U4H xn1; xn1.u = *(const uint4*)(xl + (((unsigned)s1 << 7) + off));
    float sln1 = sl06[((unsigned)s1 << 1) + h];
    for (int base = -1; base < deg; base += 4) {
        U4H xn2; xn2.u = *(const uint4*)(xl + (((unsigned)s2 << 7) + off));
        float sln2 = sl06[((unsigned)s2 << 1) + h];
        int j3 = base + 12 + e;
        int s3 = bucket[bb + min(max(j3, 0), BCAP - 1)];
        s3 = (j3 >= 0 && j3 < deg) ? s3 : d;
        bool valid = (base + e) < deg;
        __half2 sc = __floats2half2_rn(0.f, 0.f);
        sc = __hfma2(a2[0], habs2_(__hadd2(xc.h[0], xv.h[0])), sc);
        sc = __hfma2(a2[1], habs2_(__hadd2(xc.h[1], xv.h[1])), sc);
        sc = __hfma2(a2[2], habs2_(__hadd2(xc.h[2], xv.h[2])), sc);
        sc = __hfma2(a2[3], habs2_(__hadd2(xc.h[3], xv.h[3])), sc);
        float v = __low2float(sc) + __high2float(sc);
        v += __shfl_xor(v, 1, 64); v += __shfl_xor(v, 2, 64); v += __shfl_xor(v, 4, 64);
        float p = valid ? exp2f(slc + srd + v) : 0.f;
        c0 = fmaf(__low2float(xc.h[0]),  p, c0);
        c1 = fmaf(__high2float(xc.h[0]), p, c1);
        c2 = fmaf(__low2float(xc.h[1]),  p, c2);
        c3 = fmaf(__high2float(xc.h[1]), p, c3);
        c4 = fmaf(__low2float(xc.h[2]),  p, c4);
        c5 = fmaf(__high2float(xc.h[2]), p, c5);
        c6 = fmaf(__low2float(xc.h[3]),  p, c6);
        c7 = fmaf(__high2float(xc.h[3]), p, c7);
        den += p;
        xc = xn1; slc = sln1; xn1 = xn2; sln1 = sln2; s2 = s3;
    }
#pragma unroll
    for (int o = 16; o <= 32; o <<= 1) {
        c0 += __shfl_xor(c0, o, 64); c1 += __shfl_xor(c1, o, 64);
        c2 += __shfl_xor(c2, o, 64); c3 += __shfl_xor(c3, o, 64);
        c4 += __shfl_xor(c4, o, 64); c5 += __shfl_xor(c5, o, 64);
        c6 += __shfl_xor(c6, o, 64); c7 += __shfl_xor(c7, o, 64);
        den += __shfl_xor(den, o, 64);
    }
    if (e == 0) {
        float r = 1.f / den;
        __half2 o0 = __floats2half2_rn(c0 * r, c1 * r);
        __half2 o1 = __floats2half2_rn(c2 * r, c3 * r);
        __half2 o2 = __floats2half2_rn(c4 * r, c5 * r);
        __half2 o3 = __floats2half2_rn(c6 * r, c7 * r);
        uint4 out;
        __builtin_memcpy(&out.x, &o0, 4); __builtin_memcpy(&out.y, &o1, 4);
        __builtin_memcpy(&out.z, &o2, 4); __builtin_memcpy(&out.w, &o3, 4);
        *(uint4*)(h1 + (((unsigned)d << 7) + off)) = out;
    }
}

// ---------------- fused GATv2 layer 2: 8 edges/iter, 2-stage pipeline -------
__global__ void gat2_fused(const __half* __restrict__ xl, const __half* __restrict__ xr,
                           const float* __restrict__ sl06, const float* __restrict__ sr06,
                           const float* __restrict__ att,
                           const int* __restrict__ cnt, const int* __restrict__ bucket,
                           float* __restrict__ h2, int n) {
    int d = (blockIdx.x * blockDim.x + threadIdx.x) >> 6;
    if (d >= n) return;
    int lane = threadIdx.x & 63;
    int e = lane >> 3;                  // edge slot 0..7
    int off = (lane & 7) * 8;           // 8-channel base
    U4H xv; xv.u = *(const uint4*)(xr + (((unsigned)d << 6) + off));
    float4 aA = *(const float4*)(att + off);
    float4 aB = *(const float4*)(att + off + 4);
    const float S = 0.4f * LOG2E;
    __half2 a2[4];
    a2[0] = __floats2half2_rn(S * aA.x, S * aA.y);
    a2[1] = __floats2half2_rn(S * aA.z, S * aA.w);
    a2[2] = __floats2half2_rn(S * aB.x, S * aB.y);
    a2[3] = __floats2half2_rn(S * aB.z, S * aB.w);
    float srd = sr06[d];
    float c0 = 0.f, c1 = 0.f, c2 = 0.f, c3 = 0.f;
    float c4 = 0.f, c5 = 0.f, c6 = 0.f, c7 = 0.f, den = 0.f;
    int deg = cnt[d << 4];
    int bb = d * BCAP;
    int j0 = -1 + e;
    int s0 = bucket[bb + max(j0, 0)];               s0 = (j0 >= 0 && j0 < deg) ? s0 : d;
    int j1 = j0 + 8;
    int s1 = bucket[bb + min(max(j1, 0), BCAP - 1)]; s1 = (j1 >= 0 && j1 < deg) ? s1 : d;
    int j2 = j0 + 16;
    int s2 = bucket[bb + min(max(j2, 0), BCAP - 1)]; s2 = (j2 >= 0 && j2 < deg) ? s2 : d;
    U4H xc;  xc.u  = *(const uint4*)(xl + (((unsigned)s0 << 6) + off));
    float slc = sl06[s0];
    U4H xn1; xn1.u = *(const uint4*)(xl + (((unsigned)s1 << 6) + off));
    float sln1 = sl06[s1];
    for (int base = -1; base < deg; base += 8) {
        U4H xn2; xn2.u = *(const uint4*)(xl + (((unsigned)s2 << 6) + off));
        float sln2 = sl06[s2];
        int j3 = base + 24 + e;
        int s3 = bucket[bb + min(max(j3, 0), BCAP - 1)];
        s3 = (j3 >= 0 && j3 < deg) ? s3 : d;
        bool valid = (base + e) < deg;
        __half2 sc = __floats2half2_rn(0.f, 0.f);
        sc = __hfma2(a2[0], habs2_(__hadd2(xc.h[0], xv.h[0])), sc);
        sc = __hfma2(a2[1], habs2_(__hadd2(xc.h[1], xv.h[1])), sc);
        sc = __hfma2(a2[2], habs2_(__hadd2(xc.h[2], xv.h[2])), sc);
        sc = __hfma2(a2[3], habs2_(__hadd2(xc.h[3], xv.h[3])), sc);
        float v = __low2float(sc) + __high2float(sc);
        v += __shfl_xor(v, 1, 64); v += __shfl_xor(v, 2, 64); v += __shfl_xor(v, 4, 64);
        float p = valid ? exp2f(slc + srd + v) : 0.f;
        c0 = fmaf(__low2float(xc.h[0]),  p, c0);
        c1 = fmaf(__high2float(xc.h[0]), p, c1);
        c2 = fmaf(__low2float(xc.h[1]),  p, c2);
        c3 = fmaf(__high2float(xc.h[1]), p, c3);
        c4 = fmaf(__low2float(xc.h[2]),  p, c4);
        c5 = fmaf(__high2float(xc.h[2]), p, c5);
        c6 = fmaf(__low2float(xc.h[3]),  p, c6);
        c7 = fmaf(__high2float(xc.h[3]), p, c7);
        den += p;
        xc = xn1; slc = sln1; xn1 = xn2; sln1 = sln2; s2 = s3;
    }
#pragma unroll
    for (int o = 8; o <= 32; o <<= 1) {
        c0 += __shfl_xor(c0, o, 64); c1 += __shfl_xor(c1, o, 64);
        c2 += __shfl_xor(c2, o, 64); c3 += __shfl_xor(c3, o, 64);
        c4 += __shfl_xor(c4, o, 64); c5 += __shfl_xor(c5, o, 64);
        c6 += __shfl_xor(c6, o, 64); c7 += __shfl_xor(c7, o, 64);
        den += __shfl_xor(den, o, 64);
    }
    if (e == 0) {
        float r = 1.f / den;
        float4 A = {c0 * r, c1 * r, c2 * r, c3 * r};
        float4 B = {c4 * r, c5 * r, c6 * r, c7 * r};
        *(float4*)(h2 + (((unsigned)d << 6) + off))     = A;
        *(float4*)(h2 + (((unsigned)d << 6) + off + 4)) = B;
    }
}

// mean-pool over sorted batch; applies deferred elu(h + b2) while reading.
__global__ void pool_rle(const float* __restrict__ h, const float* __restrict__ b2,
                         const int* __restrict__ batch,
                         int n, int chunk, float* __restrict__ pooled,
                         float* __restrict__ counts) {
    int w = (blockIdx.x * blockDim.x + threadIdx.x) >> 6;
    int lane = threadIdx.x & 63;
    int start = w * chunk;
    int end = min(n, start + chunk);
    if (start >= end) return;
    float bv = b2[lane];
    int cur = batch[start];
    float acc = 0.f, cnt = 0.f;
    for (int node = start; node < end; node++) {
        int g = batch[node];
        if (g != cur) {
            atomicAdd(&pooled[(size_t)cur * 64 + lane], acc);
            if (lane == 0) atomicAdd(&counts[cur], cnt);
            acc = 0.f; cnt = 0.f; cur = g;
        }
        acc += elu_(h[((unsigned)node << 6) + lane] + bv);
        cnt += 1.f;
    }
    atomicAdd(&pooled[(size_t)cur * 64 + lane], acc);
    if (lane == 0) atomicAdd(&counts[cur], cnt);
}

__global__ void head(const float* __restrict__ pooled, const float* __restrict__ counts,
                     const float* __restrict__ Wlin, const float* __restrict__ blin,
                     float* __restrict__ out, int NC) {
    int g = blockIdx.x;
    int lane = threadIdx.x;
    float cnt = fmaxf(counts[g], 1.f);
    float v = pooled[(size_t)g * 64 + lane] / cnt;
    for (int j = 0; j < NC; j++) {
        float t = v * Wlin[lane * NC + j];
        for (int off = 32; off > 0; off >>= 1) t += __shfl_down(t, off, 64);
        if (lane == 0) out[g * NC + j] = t + blin[j];
    }
}

extern "C" void kernel_launch(void* const* d_in, const int* in_sizes, int n_in,
                              void* d_out, int out_size, void* d_ws, size_t ws_size,
                              hipStream_t stream) {
    const float* x    = (const float*)d_in[0];
    const int*   ei   = (const int*)d_in[1];
    const int*   batch= (const int*)d_in[2];
    const float* Wl1  = (const float*)d_in[3];
    const float* Wr1  = (const float*)d_in[4];
    const float* att1 = (const float*)d_in[5];
    const float* b1   = (const float*)d_in[6];
    const float* Wl2  = (const float*)d_in[7];
    const float* Wr2  = (const float*)d_in[8];
    const float* att2 = (const float*)d_in[9];
    const float* b2   = (const float*)d_in[10];
    const float* Wlin = (const float*)d_in[11];
    const float* blin = (const float*)d_in[12];

    const int n    = in_sizes[0] / 128;   // 50000
    const int E    = in_sizes[1] / 2;     // 600000
    const int NC   = in_sizes[12];        // 10
    const int NG   = out_size / NC;       // 64

    const int* srcA = ei;
    const int* dstA = ei + E;

    // ---- workspace layout (bytes). Aliasing: xl2+xr2 fill xl1's region,
    //      h2 fills xr1's. h1 (fp16) is kept live through gemm2.
    uint8_t* w = (uint8_t*)d_ws;
    const size_t rowB = (size_t)n * 128 * 2;     // one N x 128 16-bit tensor
    __half*         xl1 = (__half*)w;
    __half*         xr1 = (__half*)(w + rowB);
    __half*         h1  = (__half*)(w + 2 * rowB);
    __half*         xl2 = (__half*)w;                           // n*64 fp16
    __half*         xr2 = (__half*)(w + (size_t)n * 64 * 2);
    float*          h2  = (float*)(w + rowB);                   // n*64 fp32
    uint8_t* fx = w + 3 * rowB;
    unsigned short* Wl1p = (unsigned short*)fx;            fx += 16384 * 2;
    unsigned short* Wr1p = (unsigned short*)fx;            fx += 16384 * 2;
    unsigned short* Wl2p = (unsigned short*)fx;            fx += 8192 * 2;
    unsigned short* Wr2p = (unsigned short*)fx;            fx += 8192 * 2;
    float* sl1 = (float*)fx;                               fx += (size_t)n * 2 * 4;
    float* sr1 = (float*)fx;                               fx += (size_t)n * 2 * 4;
    float* sl2 = (float*)fx;                               fx += (size_t)n * 4;
    float* sr2 = (float*)fx;                               fx += (size_t)n * 4;
    float* pooled = (float*)fx;                            fx += (size_t)NG * 64 * 4;
    float* counts = (float*)fx;                            fx += (size_t)NG * 4;
    int* cnt    = (int*)fx;                                fx += (size_t)n * 16 * 4;
    int* bucket = (int*)fx;                                fx += ((size_t)n * BCAP + 64) * 4;
    if (ws_size < (size_t)(fx - (uint8_t*)d_ws)) return;   // bail visibly

    const int GB  = (n + 63) / 64;       // gemm blocks (64 nodes each)
    const int FBn = (E + 1023) / 1024;   // fill blocks (4 edges/thread)
    const int ncnt = n * 16;             // spread counters (1 per 64B line)
    const int zcb = (ncnt + 255) / 256;
    const int npool = NG * 65;           // pooled + counts (contiguous)
    const int pzb = (npool + 255) / 256;
    const int dblocks = (n + 3) / 4;     // 4 dst-waves per 256-thread block
    const int T2 = 2 * ((GB > FBn) ? GB : FBn);

    // d1: pack weights + zero cnt + zero pooled/counts
    pack_zero<<<24 + zcb + pzb, 256, 0, stream>>>(Wl1, Wr1, Wl2, Wr2,
                                                  Wl1p, Wr1p, Wl2p, Wr2p,
                                                  cnt, ncnt, zcb, pooled, npool);
    // d2: gemm layer-1 || bucket fill, interleaved even/odd
    gemm1_fill<<<T2, 256, 0, stream>>>(x, Wl1p, Wr1p, xl1, xr1, att1,
                                       sl1, sr1, n, GB, FBn,
                                       srcA, dstA, E, cnt, bucket);
    // d3..d7
    gat1_fused<<<dblocks, 256, 0, stream>>>(xl1, xr1, sl1, sr1, att1,
                                            cnt, bucket, h1, n);
    gemm2<<<GB, 256, 0, stream>>>(h1, Wl2p, Wr2p, xl2, xr2, att2, b1, sl2, sr2, n);
    gat2_fused<<<dblocks, 256, 0, stream>>>(xl2, xr2, sl2, sr2, att2,
                                            cnt, bucket, h2, n);
    {
        const int nwaves = 1024;
        const int chunk = (n + nwaves - 1) / nwaves;
        pool_rle<<<256, 256, 0, stream>>>(h2, b2, batch, n, chunk, pooled, counts);
    }
    head<<<NG, 64, 0, stream>>>(pooled, counts, Wlin, blin, (float*)d_out, NC);
}